// Round 1
// baseline (1381.942 us; speedup 1.0000x reference)
//
#include <hip/hip_runtime.h>
#include <hip/hip_bf16.h>

#define M_DIM 8192
#define N_DIM 4096
#define K_DIM 4096

#define BM 128
#define BN 128
#define BK 32   // bf16 elems along K per tile step (64 bytes per row)

typedef __attribute__((ext_vector_type(4))) float f32x4;
typedef __attribute__((ext_vector_type(8))) short bf16x8;

// ---------------------------------------------------------------------------
// Split fp32 v into bf16 hi + bf16 lo (v ~= hi + lo, error ~2^-18 relative)
// ---------------------------------------------------------------------------
__global__ __launch_bounds__(256) void split_convert(
    const float* __restrict__ in, ushort* __restrict__ hi,
    ushort* __restrict__ lo, long n) {
  long i = ((long)blockIdx.x * 256 + threadIdx.x) * 4;
  long stride = (long)gridDim.x * 256 * 4;
  for (; i < n; i += stride) {
    float4 v = *reinterpret_cast<const float4*>(in + i);
    float f[4] = {v.x, v.y, v.z, v.w};
    ushort hh[4], ll[4];
#pragma unroll
    for (int j = 0; j < 4; ++j) {
      __hip_bfloat16 hb = __float2bfloat16(f[j]);
      float r = f[j] - __bfloat162float(hb);
      __hip_bfloat16 lb = __float2bfloat16(r);
      hh[j] = *reinterpret_cast<ushort*>(&hb);
      ll[j] = *reinterpret_cast<ushort*>(&lb);
    }
    ushort4 hv; hv.x = hh[0]; hv.y = hh[1]; hv.z = hh[2]; hv.w = hh[3];
    ushort4 lv; lv.x = ll[0]; lv.y = ll[1]; lv.z = ll[2]; lv.w = ll[3];
    *reinterpret_cast<ushort4*>(hi + i) = hv;
    *reinterpret_cast<ushort4*>(lo + i) = lv;
  }
}

// ---------------------------------------------------------------------------
// global -> LDS async, 16B per lane. LDS dest must be wave-uniform base.
// ---------------------------------------------------------------------------
__device__ inline void gload_lds16(const void* g, void* l) {
  __builtin_amdgcn_global_load_lds(
      (const __attribute__((address_space(1))) void*)g,
      (__attribute__((address_space(3))) void*)l, 16, 0, 0);
}

// ---------------------------------------------------------------------------
// Split-bf16 GEMM: C = Xh*Wh^T + Xh*Wl^T + Xl*Wh^T + bias
// m97 structure: 128x128 tile, BK=32, 4 waves (2x2), 4x4 16x16x32 frags/wave
// ---------------------------------------------------------------------------
__global__ __launch_bounds__(256, 2) void gemm_split(
    const ushort* __restrict__ Xh, const ushort* __restrict__ Xl,
    const ushort* __restrict__ Wh, const ushort* __restrict__ Wl,
    const float* __restrict__ bias, float* __restrict__ out) {
  __shared__ ushort Ah[BM * BK];
  __shared__ ushort Al[BM * BK];
  __shared__ ushort Bh[BN * BK];
  __shared__ ushort Bl[BN * BK];

  const int tid = threadIdx.x;
  const int wave = tid >> 6;
  const int lane = tid & 63;
  const int wm = wave & 1;   // wave row (2 waves along M)
  const int wn = wave >> 1;  // wave col (2 waves along N)

  // XCD-aware bijective swizzle (nwg = 2048, divisible by 8)
  const int nwg = gridDim.x;
  const int per = nwg >> 3;
  const int swz = (blockIdx.x & 7) * per + (blockIdx.x >> 3);
  const int tiles_n = N_DIM / BN;  // 32
  const int tm = swz / tiles_n;
  const int tn = swz % tiles_n;

  // ---- staging geometry: each thread loads 16B x 2 issues per 8KB tile ----
  // flat byte f = iss*4096 + wave*1024 + lane*16 ; row = f>>6 ; kb = f&63
  const int srow = (wave << 4) + (lane >> 2);  // + iss*64
  const int skb = (lane & 3) << 4;

  const char* pAh0 = (const char*)Xh + (((size_t)(tm * BM + srow) * K_DIM) << 1) + skb;
  const char* pAl0 = (const char*)Xl + (((size_t)(tm * BM + srow) * K_DIM) << 1) + skb;
  const char* pBh0 = (const char*)Wh + (((size_t)(tn * BN + srow) * K_DIM) << 1) + skb;
  const char* pBl0 = (const char*)Wl + (((size_t)(tn * BN + srow) * K_DIM) << 1) + skb;
  const size_t rstep = ((size_t)64 * K_DIM) << 1;  // +64 rows (second issue)

  char* const ldsAh = (char*)Ah + (wave << 10);
  char* const ldsAl = (char*)Al + (wave << 10);
  char* const ldsBh = (char*)Bh + (wave << 10);
  char* const ldsBl = (char*)Bl + (wave << 10);

  // ---- fragment read geometry ----
  const int fr = lane & 15;
  const int fg = (lane >> 4) << 4;  // k-group byte offset (16B per group)

  f32x4 acc[4][4] = {};

  for (int k0 = 0; k0 < K_DIM; k0 += BK) {
    // stage 4 tiles (8KB each) -> 2 issues x 4 arrays
    gload_lds16(pAh0, ldsAh);
    gload_lds16(pAh0 + rstep, ldsAh + 4096);
    gload_lds16(pAl0, ldsAl);
    gload_lds16(pAl0 + rstep, ldsAl + 4096);
    gload_lds16(pBh0, ldsBh);
    gload_lds16(pBh0 + rstep, ldsBh + 4096);
    gload_lds16(pBl0, ldsBl);
    gload_lds16(pBl0 + rstep, ldsBl + 4096);
    pAh0 += 64; pAl0 += 64; pBh0 += 64; pBl0 += 64;
    __syncthreads();

    bf16x8 ah[4], al[4], bh[4], bl[4];
#pragma unroll
    for (int mi = 0; mi < 4; ++mi) {
      const int r = ((wm << 6) + (mi << 4) + fr) << 6;  // row*64 bytes
      ah[mi] = *(const bf16x8*)((const char*)Ah + r + fg);
      al[mi] = *(const bf16x8*)((const char*)Al + r + fg);
    }
#pragma unroll
    for (int ni = 0; ni < 4; ++ni) {
      const int c = ((wn << 6) + (ni << 4) + fr) << 6;
      bh[ni] = *(const bf16x8*)((const char*)Bh + c + fg);
      bl[ni] = *(const bf16x8*)((const char*)Bl + c + fg);
    }

#pragma unroll
    for (int mi = 0; mi < 4; ++mi) {
#pragma unroll
      for (int ni = 0; ni < 4; ++ni) {
        acc[mi][ni] = __builtin_amdgcn_mfma_f32_16x16x32_bf16(ah[mi], bh[ni], acc[mi][ni], 0, 0, 0);
        acc[mi][ni] = __builtin_amdgcn_mfma_f32_16x16x32_bf16(ah[mi], bl[ni], acc[mi][ni], 0, 0, 0);
        acc[mi][ni] = __builtin_amdgcn_mfma_f32_16x16x32_bf16(al[mi], bh[ni], acc[mi][ni], 0, 0, 0);
      }
    }
    __syncthreads();
  }

  // ---- epilogue: C layout col = lane&15, row = (lane>>4)*4 + i ----
  const int row0 = tm * BM + (wm << 6);
  const int col0 = tn * BN + (wn << 6);
  const int cr = (lane >> 4) << 2;
  const int cc = lane & 15;
#pragma unroll
  for (int ni = 0; ni < 4; ++ni) {
    const int c = col0 + (ni << 4) + cc;
    const float bv = bias[c];
#pragma unroll
    for (int mi = 0; mi < 4; ++mi) {
#pragma unroll
      for (int i = 0; i < 4; ++i) {
        out[(size_t)(row0 + (mi << 4) + cr + i) * N_DIM + c] = acc[mi][ni][i] + bv;
      }
    }
  }
}

// ---------------------------------------------------------------------------
// Fallback: plain fp32 LDS-tiled GEMM (used only if ws too small)
// ---------------------------------------------------------------------------
__global__ __launch_bounds__(256) void gemm_fallback(
    const float* __restrict__ X, const float* __restrict__ W,
    const float* __restrict__ bias, float* __restrict__ out) {
  __shared__ float As[64][17];
  __shared__ float Bs[64][17];
  const int tid = threadIdx.x;
  const int tm = blockIdx.x / (N_DIM / 64);
  const int tn = blockIdx.x % (N_DIM / 64);
  const int ty = tid >> 4, tx = tid & 15;
  float acc[4][4] = {};
  for (int k0 = 0; k0 < K_DIM; k0 += 16) {
#pragma unroll
    for (int i = 0; i < 4; ++i) {
      int idx = tid * 4 + i;
      int r = idx >> 4, c = idx & 15;
      As[r][c] = X[(size_t)(tm * 64 + r) * K_DIM + k0 + c];
      Bs[r][c] = W[(size_t)(tn * 64 + r) * K_DIM + k0 + c];
    }
    __syncthreads();
#pragma unroll
    for (int kk = 0; kk < 16; ++kk)
#pragma unroll
      for (int i = 0; i < 4; ++i)
#pragma unroll
        for (int j = 0; j < 4; ++j)
          acc[i][j] += As[ty * 4 + i][kk] * Bs[tx * 4 + j][kk];
    __syncthreads();
  }
#pragma unroll
  for (int i = 0; i < 4; ++i)
#pragma unroll
    for (int j = 0; j < 4; ++j) {
      int c = tn * 64 + tx * 4 + j;
      out[(size_t)(tm * 64 + ty * 4 + i) * N_DIM + c] = acc[i][j] + bias[c];
    }
}

extern "C" void kernel_launch(void* const* d_in, const int* in_sizes, int n_in,
                              void* d_out, int out_size, void* d_ws, size_t ws_size,
                              hipStream_t stream) {
  const float* X = (const float*)d_in[0];
  const float* W = (const float*)d_in[1];
  const float* bias = (const float*)d_in[2];
  float* out = (float*)d_out;

  const size_t nX = (size_t)M_DIM * K_DIM;
  const size_t nW = (size_t)N_DIM * K_DIM;
  const size_t needed = (nX + nW) * 2 * sizeof(ushort);  // hi+lo for X and W

  if (ws_size >= needed) {
    ushort* Xh = (ushort*)d_ws;
    ushort* Xl = Xh + nX;
    ushort* Wh = Xl + nX;
    ushort* Wl = Wh + nW;
    split_convert<<<2048, 256, 0, stream>>>(X, Xh, Xl, (long)nX);
    split_convert<<<1024, 256, 0, stream>>>(W, Wh, Wl, (long)nW);
    const int grid = (M_DIM / BM) * (N_DIM / BN);  // 64*32 = 2048
    gemm_split<<<grid, 256, 0, stream>>>(Xh, Xl, Wh, Wl, bias, out);
  } else {
    gemm_fallback<<<(M_DIM / 64) * (N_DIM / 64), 256, 0, stream>>>(X, W, bias, out);
  }
}

// Round 2
// 939.537 us; speedup vs baseline: 1.4709x; 1.4709x over previous
//
#include <hip/hip_runtime.h>
#include <hip/hip_bf16.h>

#define M_DIM 8192
#define N_DIM 4096
#define K_DIM 4096
#define KC (3 * K_DIM)        // 12288 concatenated K
#define NT (KC / 64)          // 192 K-tiles of 64
#define PITCH_B 16384         // bytes per row of Xhl/Whl (8192 bf16)
#define HALF_G ((size_t)128 * PITCH_B)
#define ISS_G ((size_t)64 * PITCH_B)

typedef __attribute__((ext_vector_type(4))) float f32x4;
typedef __attribute__((ext_vector_type(8))) short bf16x8;

#define GLOAD(src, dst)                                                        \
  __builtin_amdgcn_global_load_lds(                                            \
      (const __attribute__((address_space(1))) void*)(src),                    \
      (__attribute__((address_space(3))) void*)(dst), 16, 0, 0)

#define MFMA(a, b, c) __builtin_amdgcn_mfma_f32_16x16x32_bf16((a), (b), (c), 0, 0, 0)

// ---------------------------------------------------------------------------
// fp32 -> (hi,lo) bf16 split, written into [rows][2W]: [r][c]=hi, [r][c+W]=lo
// ---------------------------------------------------------------------------
__global__ __launch_bounds__(256) void split_convert(
    const float* __restrict__ in, ushort* __restrict__ out, long n) {
  long i = ((long)blockIdx.x * 256 + threadIdx.x) * 4;
  const long stride = (long)gridDim.x * 1024;
  for (; i < n; i += stride) {
    float4 v = *reinterpret_cast<const float4*>(in + i);
    float f[4] = {v.x, v.y, v.z, v.w};
    ushort hh[4], ll[4];
#pragma unroll
    for (int j = 0; j < 4; ++j) {
      __hip_bfloat16 hb = __float2bfloat16(f[j]);
      float r = f[j] - __bfloat162float(hb);
      __hip_bfloat16 lb = __float2bfloat16(r);
      hh[j] = *reinterpret_cast<ushort*>(&hb);
      ll[j] = *reinterpret_cast<ushort*>(&lb);
    }
    ushort4 hv; hv.x = hh[0]; hv.y = hh[1]; hv.z = hh[2]; hv.w = hh[3];
    ushort4 lv; lv.x = ll[0]; lv.y = ll[1]; lv.z = ll[2]; lv.w = ll[3];
    long r = i >> 12;            // row (W = 4096)
    long c = i & 4095;
    long o = (r << 13) + c;      // row pitch 8192
    *reinterpret_cast<ushort4*>(out + o) = hv;
    *reinterpret_cast<ushort4*>(out + o + 4096) = lv;
  }
}

// K-region column byte offsets: A = [Xh | Xl | Xh], B = [Wh | Wh | Wl]
__device__ __forceinline__ int colA_bytes(int t) { return ((t < 128) ? t : t - 128) << 7; }
__device__ __forceinline__ int colB_bytes(int t) { return ((t < 64) ? t : t - 64) << 7; }

// stage one 128-row half-tile (16KB): 2 gloads/wave, 1KB/wave each issue.
__device__ __forceinline__ void stage_half(const char* g, char* l, int wave) {
  GLOAD(g, l + (wave << 10));
  GLOAD(g + ISS_G, l + 8192 + (wave << 10));
}

// ---------------------------------------------------------------------------
// one K-tile (K=64) of the 8-phase schedule (4 phases per tile, x2 tiles/iter)
// MODE 0: full staging + vmcnt(6); 1: only A1(t+1) stage + vmcnt(0); 2: none.
// ---------------------------------------------------------------------------
template <int MODE>
__device__ __forceinline__ void do_tile(
    char* aC, char* bC, char* aN,
    const char* gA1, const char* gB2, const char* gA2,
    int wave, int fr, int cb0, f32x4 (&acc)[16][2]) {
  bf16x8 bf[2][2];
  // ---------------- phase 0: B-all + A-quad0 reads; stage A1(t+1) ----------
  {
    bf16x8 af[4][2];
#pragma unroll
    for (int m4 = 0; m4 < 4; ++m4) {
      const char* ra = aC + (m4 << 11) + (fr << 7);
      af[m4][0] = *(const bf16x8*)(ra + cb0);
      af[m4][1] = *(const bf16x8*)(ra + (cb0 ^ 64));
    }
#pragma unroll
    for (int ni = 0; ni < 2; ++ni) {
      const char* rb = bC + (((wave << 5) + (ni << 4) + fr) << 7);
      bf[ni][0] = *(const bf16x8*)(rb + cb0);
      bf[ni][1] = *(const bf16x8*)(rb + (cb0 ^ 64));
    }
    if (MODE < 2) stage_half(gA1 + HALF_G, aN + 16384, wave);
    __builtin_amdgcn_sched_barrier(0);
    __builtin_amdgcn_s_barrier();
    asm volatile("s_waitcnt lgkmcnt(0)" ::: "memory");
    __builtin_amdgcn_sched_barrier(0);
    __builtin_amdgcn_s_setprio(1);
#pragma unroll
    for (int m4 = 0; m4 < 4; ++m4)
#pragma unroll
      for (int ni = 0; ni < 2; ++ni) {
        acc[m4][ni] = MFMA(af[m4][0], bf[ni][0], acc[m4][ni]);
        acc[m4][ni] = MFMA(af[m4][1], bf[ni][1], acc[m4][ni]);
      }
    __builtin_amdgcn_s_setprio(0);
    __builtin_amdgcn_s_barrier();
  }
  // ---------------- phases 1..3: A-quad reads; stage B0,B1,A0 of (t+2) -----
#pragma unroll
  for (int p = 1; p < 4; ++p) {
    bf16x8 af[4][2];
#pragma unroll
    for (int m4 = 0; m4 < 4; ++m4) {
      const char* ra = aC + (((p << 2) + m4) << 11) + (fr << 7);
      af[m4][0] = *(const bf16x8*)(ra + cb0);
      af[m4][1] = *(const bf16x8*)(ra + (cb0 ^ 64));
    }
    if (MODE == 0) {
      if (p == 1) stage_half(gB2, bC, wave);
      if (p == 2) stage_half(gB2 + HALF_G, bC + 16384, wave);
      if (p == 3) stage_half(gA2, aC, wave);
    }
    if (p == 3) {
      if (MODE == 0) asm volatile("s_waitcnt vmcnt(6)" ::: "memory");
      if (MODE == 1) asm volatile("s_waitcnt vmcnt(0)" ::: "memory");
    }
    __builtin_amdgcn_sched_barrier(0);
    __builtin_amdgcn_s_barrier();
    asm volatile("s_waitcnt lgkmcnt(0)" ::: "memory");
    __builtin_amdgcn_sched_barrier(0);
    __builtin_amdgcn_s_setprio(1);
#pragma unroll
    for (int m4 = 0; m4 < 4; ++m4)
#pragma unroll
      for (int ni = 0; ni < 2; ++ni) {
        acc[(p << 2) + m4][ni] = MFMA(af[m4][0], bf[ni][0], acc[(p << 2) + m4][ni]);
        acc[(p << 2) + m4][ni] = MFMA(af[m4][1], bf[ni][1], acc[(p << 2) + m4][ni]);
      }
    __builtin_amdgcn_s_setprio(0);
    __builtin_amdgcn_s_barrier();
  }
}

// ---------------------------------------------------------------------------
// 256x256 8-phase bf16 GEMM over concatenated K'=12288.
// 8 waves (1M x 8N): per-wave 256 rows x 32 cols, acc[16][2] f32x4.
// ---------------------------------------------------------------------------
__global__ __launch_bounds__(512, 2) void gemm8(
    const ushort* __restrict__ Xhl, const ushort* __restrict__ Whl,
    const float* __restrict__ bias, float* __restrict__ out) {
  __shared__ __align__(16) char lds[131072];

  const int tid = threadIdx.x;
  const int wave = tid >> 6;
  const int lane = tid & 63;

  // T1: XCD-aware bijective swizzle (512 blocks, 512 % 8 == 0)
  const int swz = ((blockIdx.x & 7) << 6) + (blockIdx.x >> 3);
  const int tm = swz >> 4, tn = swz & 15;     // 32 x 16 tiles
  const int brow0 = tm << 8, bcol0 = tn << 8;

  // staging geometry: lds flat f = iss*8192 + wave*1024 + lane*16
  // row = h*128 + iss*64 + wave*8 + (lane>>3); stored-at cb_swz=(lane&7)<<4;
  // logical col = cb_swz ^ ((row&7)<<4)  (involution, row&7 == lane>>3)
  const int s_r0 = (wave << 3) + (lane >> 3);
  const int s_cb = ((lane & 7) ^ (lane >> 3)) << 4;
  const char* gX = (const char*)Xhl + (size_t)(brow0 + s_r0) * PITCH_B + s_cb;
  const char* gW = (const char*)Whl + (size_t)(bcol0 + s_r0) * PITCH_B + s_cb;

  // fragment geometry: addr = row*128 + (cb_log ^ ((row&7)<<4)), row&7==lane&7
  const int fr = lane & 15;
  const int cb0 = (((lane >> 4) << 4) ^ ((lane & 7) << 4));

  f32x4 acc[16][2];
#pragma unroll
  for (int i = 0; i < 16; ++i) {
    acc[i][0] = (f32x4){0.f, 0.f, 0.f, 0.f};
    acc[i][1] = (f32x4){0.f, 0.f, 0.f, 0.f};
  }

  char* A0 = lds;
  char* B0 = lds + 32768;
  char* A1 = lds + 65536;
  char* B1 = lds + 98304;

  // prologue: tile0 {B0,B1,A0,A1} + tile1 {B0,B1,A0}; drain to tile0 complete
  {
    const char* gB0s = gW + colB_bytes(0);
    const char* gA0s = gX + colA_bytes(0);
    const char* gB1s = gW + colB_bytes(1);
    const char* gA1s = gX + colA_bytes(1);
    stage_half(gB0s, B0, wave);
    stage_half(gB0s + HALF_G, B0 + 16384, wave);
    stage_half(gA0s, A0, wave);
    stage_half(gA0s + HALF_G, A0 + 16384, wave);
    stage_half(gB1s, B1, wave);
    stage_half(gB1s + HALF_G, B1 + 16384, wave);
    stage_half(gA1s, A1, wave);
    asm volatile("s_waitcnt vmcnt(6)" ::: "memory");
    __builtin_amdgcn_s_barrier();
  }

  for (int t = 0; t < NT - 2; ++t) {
    const int bt = t & 1;
    char* aC = lds + (bt << 16);
    char* bC = aC + 32768;
    char* aN = lds + ((bt ^ 1) << 16);
    do_tile<0>(aC, bC, aN, gX + colA_bytes(t + 1), gW + colB_bytes(t + 2),
               gX + colA_bytes(t + 2), wave, fr, cb0, acc);
  }
  // t = NT-2 (= 190, even -> buf0): stage only A1(191), drain all
  do_tile<1>(A0, B0, A1, gX + colA_bytes(NT - 1), gW, gX, wave, fr, cb0, acc);
  // t = NT-1 (buf1): pure compute
  do_tile<2>(A1, B1, A0, gX, gW, gX, wave, fr, cb0, acc);

  // epilogue: C[col=lane&15, row=(lane>>4)*4+j] per 16x16 frag
  const int c_col = bcol0 + (wave << 5) + fr;
  const size_t rbase = (size_t)brow0 + ((lane >> 4) << 2);
  const float bv0 = bias[c_col];
  const float bv1 = bias[c_col + 16];
#pragma unroll
  for (int mi = 0; mi < 16; ++mi) {
#pragma unroll
    for (int j = 0; j < 4; ++j) {
      const size_t r = rbase + (mi << 4) + j;
      out[r * N_DIM + c_col] = acc[mi][0][j] + bv0;
      out[r * N_DIM + c_col + 16] = acc[mi][1][j] + bv1;
    }
  }
}

// ---------------------------------------------------------------------------
// Fallback: plain fp32 LDS-tiled GEMM (only if ws too small)
// ---------------------------------------------------------------------------
__global__ __launch_bounds__(256) void gemm_fallback(
    const float* __restrict__ X, const float* __restrict__ W,
    const float* __restrict__ bias, float* __restrict__ out) {
  __shared__ float As[64][17];
  __shared__ float Bs[64][17];
  const int tid = threadIdx.x;
  const int tm = blockIdx.x / (N_DIM / 64);
  const int tn = blockIdx.x % (N_DIM / 64);
  const int ty = tid >> 4, tx = tid & 15;
  float acc[4][4] = {};
  for (int k0 = 0; k0 < K_DIM; k0 += 16) {
#pragma unroll
    for (int i = 0; i < 4; ++i) {
      int idx = tid * 4 + i;
      int r = idx >> 4, c = idx & 15;
      As[r][c] = X[(size_t)(tm * 64 + r) * K_DIM + k0 + c];
      Bs[r][c] = W[(size_t)(tn * 64 + r) * K_DIM + k0 + c];
    }
    __syncthreads();
#pragma unroll
    for (int kk = 0; kk < 16; ++kk)
#pragma unroll
      for (int i = 0; i < 4; ++i)
#pragma unroll
        for (int j = 0; j < 4; ++j)
          acc[i][j] += As[ty * 4 + i][kk] * Bs[tx * 4 + j][kk];
    __syncthreads();
  }
#pragma unroll
  for (int i = 0; i < 4; ++i)
#pragma unroll
    for (int j = 0; j < 4; ++j) {
      int c = tn * 64 + tx * 4 + j;
      out[(size_t)(tm * 64 + ty * 4 + i) * N_DIM + c] = acc[i][j] + bias[c];
    }
}

extern "C" void kernel_launch(void* const* d_in, const int* in_sizes, int n_in,
                              void* d_out, int out_size, void* d_ws, size_t ws_size,
                              hipStream_t stream) {
  const float* X = (const float*)d_in[0];
  const float* W = (const float*)d_in[1];
  const float* bias = (const float*)d_in[2];
  float* out = (float*)d_out;

  const size_t nXhl = (size_t)M_DIM * 8192;  // 67.1M ushort = 128MB
  const size_t nWhl = (size_t)N_DIM * 8192;  // 33.5M ushort = 64MB
  const size_t needed = (nXhl + nWhl) * sizeof(ushort);

  if (ws_size >= needed) {
    ushort* Xhl = (ushort*)d_ws;
    ushort* Whl = Xhl + nXhl;
    split_convert<<<2048, 256, 0, stream>>>(X, Xhl, (long)M_DIM * K_DIM);
    split_convert<<<1024, 256, 0, stream>>>(W, Whl, (long)N_DIM * K_DIM);
    gemm8<<<512, 512, 0, stream>>>(Xhl, Whl, bias, out);
  } else {
    gemm_fallback<<<(M_DIM / 64) * (N_DIM / 64), 256, 0, stream>>>(X, W, bias, out);
  }
}

// Round 3
// 883.341 us; speedup vs baseline: 1.5644x; 1.0636x over previous
//
#include <hip/hip_runtime.h>
#include <hip/hip_bf16.h>

#define M_DIM 8192
#define N_DIM 4096
#define K_DIM 4096
#define KC (3 * K_DIM)        // 12288 concatenated K
#define NT (KC / 64)          // 192 K-tiles of 64
#define PITCH_B 16384         // bytes per row of Xhl/Whl (8192 bf16)
#define HALF_G ((size_t)128 * PITCH_B)
#define ISS_G ((size_t)64 * PITCH_B)

typedef __attribute__((ext_vector_type(4))) float f32x4;
typedef __attribute__((ext_vector_type(8))) short bf16x8;

#define GLOAD(src, dst)                                                        \
  __builtin_amdgcn_global_load_lds(                                            \
      (const __attribute__((address_space(1))) void*)(src),                    \
      (__attribute__((address_space(3))) void*)(dst), 16, 0, 0)

#define MFMA(a, b, c) __builtin_amdgcn_mfma_f32_16x16x32_bf16((a), (b), (c), 0, 0, 0)

// ---------------------------------------------------------------------------
// fp32 -> (hi,lo) bf16 split, written into [rows][2W]: [r][c]=hi, [r][c+W]=lo
// ---------------------------------------------------------------------------
__global__ __launch_bounds__(256) void split_convert(
    const float* __restrict__ in, ushort* __restrict__ out, long n) {
  long i = ((long)blockIdx.x * 256 + threadIdx.x) * 4;
  const long stride = (long)gridDim.x * 1024;
  for (; i < n; i += stride) {
    float4 v = *reinterpret_cast<const float4*>(in + i);
    float f[4] = {v.x, v.y, v.z, v.w};
    ushort hh[4], ll[4];
#pragma unroll
    for (int j = 0; j < 4; ++j) {
      __hip_bfloat16 hb = __float2bfloat16(f[j]);
      float r = f[j] - __bfloat162float(hb);
      __hip_bfloat16 lb = __float2bfloat16(r);
      hh[j] = *reinterpret_cast<ushort*>(&hb);
      ll[j] = *reinterpret_cast<ushort*>(&lb);
    }
    ushort4 hv; hv.x = hh[0]; hv.y = hh[1]; hv.z = hh[2]; hv.w = hh[3];
    ushort4 lv; lv.x = ll[0]; lv.y = ll[1]; lv.z = ll[2]; lv.w = ll[3];
    long r = i >> 12;            // row (W = 4096)
    long c = i & 4095;
    long o = (r << 13) + c;      // row pitch 8192
    *reinterpret_cast<ushort4*>(out + o) = hv;
    *reinterpret_cast<ushort4*>(out + o + 4096) = lv;
  }
}

// K-region column byte offsets: A = [Xh | Xl | Xh], B = [Wh | Wh | Wl]
__device__ __forceinline__ int colA_bytes(int t) { return ((t < 128) ? t : t - 128) << 7; }
__device__ __forceinline__ int colB_bytes(int t) { return ((t < 64) ? t : t - 64) << 7; }

// stage one 128-row half-tile (16KB): 2 gloads/wave, 1KB/wave each issue.
__device__ __forceinline__ void stage_half(const char* g, char* l, int wave) {
  GLOAD(g, l + (wave << 10));
  GLOAD(g + ISS_G, l + 8192 + (wave << 10));
}

// ---------------------------------------------------------------------------
// one K-tile (K=64), 4 phases. Wave decomposition 2M x 4N: per-wave 128x64.
// Per phase: 4 A ds_reads (+8 B reads at p0, held in regs) + 16 MFMA.
// MODE 0: full staging + vmcnt(6); 1: only A1(t+1) stage + vmcnt(0); 2: none.
// ---------------------------------------------------------------------------
template <int MODE>
__device__ __forceinline__ void do_tile(
    char* aC, char* bC, char* aN,
    const char* gA1, const char* gB2, const char* gA2,
    int wm, int wn, int wave, int fr, int cb0, f32x4 (&acc)[8][4]) {
  bf16x8 bf[4][2];
#pragma unroll
  for (int p = 0; p < 4; ++p) {
    bf16x8 af[2][2];
#pragma unroll
    for (int mi = 0; mi < 2; ++mi) {
      const char* ra = aC + (((wm << 7) + (p << 5) + (mi << 4) + fr) << 7);
      af[mi][0] = *(const bf16x8*)(ra + cb0);
      af[mi][1] = *(const bf16x8*)(ra + (cb0 ^ 64));
    }
    if (p == 0) {
#pragma unroll
      for (int ni = 0; ni < 4; ++ni) {
        const char* rb = bC + (((wn << 6) + (ni << 4) + fr) << 7);
        bf[ni][0] = *(const bf16x8*)(rb + cb0);
        bf[ni][1] = *(const bf16x8*)(rb + (cb0 ^ 64));
      }
      if (MODE < 2) stage_half(gA1 + HALF_G, aN + 16384, wave);
    }
    if (MODE == 0) {
      if (p == 1) stage_half(gB2, bC, wave);
      if (p == 2) stage_half(gB2 + 16384 * 0 + HALF_G, bC + 16384, wave);
      if (p == 3) stage_half(gA2, aC, wave);
    }
    if (p == 3) {
      if (MODE == 0) asm volatile("s_waitcnt vmcnt(6)" ::: "memory");
      if (MODE == 1) asm volatile("s_waitcnt vmcnt(0)" ::: "memory");
    }
    __builtin_amdgcn_sched_barrier(0);
    __builtin_amdgcn_s_barrier();
    asm volatile("s_waitcnt lgkmcnt(0)" ::: "memory");
    __builtin_amdgcn_sched_barrier(0);
    __builtin_amdgcn_s_setprio(1);
#pragma unroll
    for (int mi = 0; mi < 2; ++mi)
#pragma unroll
      for (int ni = 0; ni < 4; ++ni) {
        acc[(p << 1) + mi][ni] = MFMA(af[mi][0], bf[ni][0], acc[(p << 1) + mi][ni]);
        acc[(p << 1) + mi][ni] = MFMA(af[mi][1], bf[ni][1], acc[(p << 1) + mi][ni]);
      }
    __builtin_amdgcn_s_setprio(0);
    __builtin_amdgcn_s_barrier();
  }
}

// ---------------------------------------------------------------------------
// 256x256 8-phase bf16 GEMM over concatenated K'=12288.
// 8 waves (2M x 4N): per-wave 128 rows x 64 cols, acc[8][4] f32x4.
// ---------------------------------------------------------------------------
__global__ __launch_bounds__(512, 2) void gemm8(
    const ushort* __restrict__ Xhl, const ushort* __restrict__ Whl,
    const float* __restrict__ bias, float* __restrict__ out) {
  __shared__ __align__(16) char lds[131072];

  const int tid = threadIdx.x;
  const int wave = tid >> 6;
  const int lane = tid & 63;
  const int wm = wave & 1;   // 2 waves along M
  const int wn = wave >> 1;  // 4 waves along N

  // T1: XCD-aware bijective swizzle (512 blocks, 512 % 8 == 0)
  const int swz = ((blockIdx.x & 7) << 6) + (blockIdx.x >> 3);
  const int tm = swz >> 4, tn = swz & 15;     // 32 x 16 tiles
  const int brow0 = tm << 8, bcol0 = tn << 8;

  // staging geometry: lds flat f = iss*8192 + wave*1024 + lane*16
  // row = h*128 + iss*64 + wave*8 + (lane>>3); stored-at cb_swz=(lane&7)<<4;
  // logical col = cb_swz ^ ((row&7)<<4)  (involution, row&7 == lane>>3)
  const int s_r0 = (wave << 3) + (lane >> 3);
  const int s_cb = ((lane & 7) ^ (lane >> 3)) << 4;
  const char* gX = (const char*)Xhl + (size_t)(brow0 + s_r0) * PITCH_B + s_cb;
  const char* gW = (const char*)Whl + (size_t)(bcol0 + s_r0) * PITCH_B + s_cb;

  // fragment geometry: addr = row*128 + (cb_log ^ ((row&7)<<4)), row&7==lane&7
  const int fr = lane & 15;
  const int cb0 = (((lane >> 4) << 4) ^ ((lane & 7) << 4));

  f32x4 acc[8][4];
#pragma unroll
  for (int i = 0; i < 8; ++i)
#pragma unroll
    for (int j = 0; j < 4; ++j) acc[i][j] = (f32x4){0.f, 0.f, 0.f, 0.f};

  char* A0 = lds;
  char* B0 = lds + 32768;
  char* A1 = lds + 65536;
  char* B1 = lds + 98304;

  // prologue: tile0 {B0,B1,A0,A1} + tile1 {B0,B1,A0h0}; drain to tile0 ready
  {
    const char* gB0s = gW + colB_bytes(0);
    const char* gA0s = gX + colA_bytes(0);
    const char* gB1s = gW + colB_bytes(1);
    const char* gA1s = gX + colA_bytes(1);
    stage_half(gB0s, B0, wave);
    stage_half(gB0s + HALF_G, B0 + 16384, wave);
    stage_half(gA0s, A0, wave);
    stage_half(gA0s + HALF_G, A0 + 16384, wave);
    stage_half(gB1s, B1, wave);
    stage_half(gB1s + HALF_G, B1 + 16384, wave);
    stage_half(gA1s, A1, wave);
    asm volatile("s_waitcnt vmcnt(6)" ::: "memory");
    __builtin_amdgcn_s_barrier();
  }

  for (int t = 0; t < NT - 2; ++t) {
    const int bt = t & 1;
    char* aC = lds + (bt << 16);
    char* bC = aC + 32768;
    char* aN = lds + ((bt ^ 1) << 16);
    do_tile<0>(aC, bC, aN, gX + colA_bytes(t + 1), gW + colB_bytes(t + 2),
               gX + colA_bytes(t + 2), wm, wn, wave, fr, cb0, acc);
  }
  // t = NT-2 (= 190, even -> buf0): stage only A1(191) half1, drain all
  do_tile<1>(A0, B0, A1, gX + colA_bytes(NT - 1), gW, gX, wm, wn, wave, fr, cb0, acc);
  // t = NT-1 (buf1): pure compute
  do_tile<2>(A1, B1, A0, gX, gW, gX, wm, wn, wave, fr, cb0, acc);

  // epilogue: per 16x16 frag, C[col = lane&15, row = (lane>>4)*4 + j]
  const int ccol = bcol0 + (wn << 6) + fr;
  const size_t rbase = (size_t)brow0 + (wm << 7) + ((lane >> 4) << 2);
  float bv[4];
#pragma unroll
  for (int ni = 0; ni < 4; ++ni) bv[ni] = bias[ccol + (ni << 4)];
#pragma unroll
  for (int mi = 0; mi < 8; ++mi) {
#pragma unroll
    for (int j = 0; j < 4; ++j) {
      float* orow = out + (rbase + (mi << 4) + j) * N_DIM;
#pragma unroll
      for (int ni = 0; ni < 4; ++ni)
        orow[ccol + (ni << 4)] = acc[mi][ni][j] + bv[ni];
    }
  }
}

// ---------------------------------------------------------------------------
// Fallback: plain fp32 LDS-tiled GEMM (only if ws too small)
// ---------------------------------------------------------------------------
__global__ __launch_bounds__(256) void gemm_fallback(
    const float* __restrict__ X, const float* __restrict__ W,
    const float* __restrict__ bias, float* __restrict__ out) {
  __shared__ float As[64][17];
  __shared__ float Bs[64][17];
  const int tid = threadIdx.x;
  const int tm = blockIdx.x / (N_DIM / 64);
  const int tn = blockIdx.x % (N_DIM / 64);
  const int ty = tid >> 4, tx = tid & 15;
  float acc[4][4] = {};
  for (int k0 = 0; k0 < K_DIM; k0 += 16) {
#pragma unroll
    for (int i = 0; i < 4; ++i) {
      int idx = tid * 4 + i;
      int r = idx >> 4, c = idx & 15;
      As[r][c] = X[(size_t)(tm * 64 + r) * K_DIM + k0 + c];
      Bs[r][c] = W[(size_t)(tn * 64 + r) * K_DIM + k0 + c];
    }
    __syncthreads();
#pragma unroll
    for (int kk = 0; kk < 16; ++kk)
#pragma unroll
      for (int i = 0; i < 4; ++i)
#pragma unroll
        for (int j = 0; j < 4; ++j)
          acc[i][j] += As[ty * 4 + i][kk] * Bs[tx * 4 + j][kk];
    __syncthreads();
  }
#pragma unroll
  for (int i = 0; i < 4; ++i)
#pragma unroll
    for (int j = 0; j < 4; ++j) {
      int c = tn * 64 + tx * 4 + j;
      out[(size_t)(tm * 64 + ty * 4 + i) * N_DIM + c] = acc[i][j] + bias[c];
    }
}

extern "C" void kernel_launch(void* const* d_in, const int* in_sizes, int n_in,
                              void* d_out, int out_size, void* d_ws, size_t ws_size,
                              hipStream_t stream) {
  const float* X = (const float*)d_in[0];
  const float* W = (const float*)d_in[1];
  const float* bias = (const float*)d_in[2];
  float* out = (float*)d_out;

  const size_t nXhl = (size_t)M_DIM * 8192;  // 128MB
  const size_t nWhl = (size_t)N_DIM * 8192;  // 64MB
  const size_t needed = (nXhl + nWhl) * sizeof(ushort);

  if (ws_size >= needed) {
    ushort* Xhl = (ushort*)d_ws;
    ushort* Whl = Xhl + nXhl;
    split_convert<<<2048, 256, 0, stream>>>(X, Xhl, (long)M_DIM * K_DIM);
    split_convert<<<1024, 256, 0, stream>>>(W, Whl, (long)N_DIM * K_DIM);
    gemm8<<<512, 512, 0, stream>>>(Xhl, Whl, bias, out);
  } else {
    gemm_fallback<<<(M_DIM / 64) * (N_DIM / 64), 256, 0, stream>>>(X, W, bias, out);
  }
}

// Round 8
// 504.967 us; speedup vs baseline: 2.7367x; 1.7493x over previous
//
#include <hip/hip_runtime.h>
#include <hip/hip_bf16.h>

#define M_DIM 8192
#define N_DIM 4096
#define K_DIM 4096
#define NT (K_DIM / 64)       // 64 K-tiles of 64
#define PITCH_B 8192          // bytes per row of Xh/Wh (4096 bf16)
#define HALF_G ((size_t)128 * PITCH_B)
#define ISS_G ((size_t)64 * PITCH_B)

typedef __attribute__((ext_vector_type(4))) float f32x4;
typedef __attribute__((ext_vector_type(8))) short bf16x8;

#define GLOAD(src, dst)                                                        \
  __builtin_amdgcn_global_load_lds(                                            \
      (const __attribute__((address_space(1))) void*)(src),                    \
      (__attribute__((address_space(3))) void*)(dst), 16, 0, 0)

#define MFMA(a, b, c) __builtin_amdgcn_mfma_f32_16x16x32_bf16((a), (b), (c), 0, 0, 0)

// ---------------------------------------------------------------------------
// fp32 -> bf16 (RN), flat layout
// ---------------------------------------------------------------------------
__global__ __launch_bounds__(256) void convert_bf16(
    const float* __restrict__ in, ushort* __restrict__ out, long n) {
  long i = ((long)blockIdx.x * 256 + threadIdx.x) * 4;
  const long stride = (long)gridDim.x * 1024;
  for (; i < n; i += stride) {
    float4 v = *reinterpret_cast<const float4*>(in + i);
    float f[4] = {v.x, v.y, v.z, v.w};
    ushort h[4];
#pragma unroll
    for (int j = 0; j < 4; ++j) {
      __hip_bfloat16 hb = __float2bfloat16(f[j]);
      h[j] = *reinterpret_cast<ushort*>(&hb);
    }
    ushort4 hv; hv.x = h[0]; hv.y = h[1]; hv.z = h[2]; hv.w = h[3];
    *reinterpret_cast<ushort4*>(out + i) = hv;
  }
}

// K-tile t -> column byte offset (64 bf16 = 128 B per tile)
__device__ __forceinline__ int col_bytes(int t) { return t << 7; }

// stage one 128-row half-tile (16KB): 2 gloads/wave, 1KB/wave each issue.
__device__ __forceinline__ void stage_half(const char* g, char* l, int wave) {
  GLOAD(g, l + (wave << 10));
  GLOAD(g + ISS_G, l + 8192 + (wave << 10));
}

// ---------------------------------------------------------------------------
// one K-tile (K=64), 4 phases. Wave decomposition 2M x 4N: per-wave 128x64.
// Per phase: 4 A ds_reads (+8 B reads at p0, held in regs) + 16 MFMA.
// MODE 0: full staging + vmcnt(6); 1: only A(t+1)h1 stage + vmcnt(0); 2: none.
// ---------------------------------------------------------------------------
template <int MODE>
__device__ __forceinline__ void do_tile(
    char* aC, char* bC, char* aN,
    const char* gA1, const char* gB2, const char* gA2,
    int wm, int wn, int wave, int fr, int cb0, f32x4 (&acc)[8][4]) {
  bf16x8 bf[4][2];
#pragma unroll
  for (int p = 0; p < 4; ++p) {
    bf16x8 af[2][2];
#pragma unroll
    for (int mi = 0; mi < 2; ++mi) {
      const char* ra = aC + (((wm << 7) + (p << 5) + (mi << 4) + fr) << 7);
      af[mi][0] = *(const bf16x8*)(ra + cb0);
      af[mi][1] = *(const bf16x8*)(ra + (cb0 ^ 64));
    }
    if (p == 0) {
#pragma unroll
      for (int ni = 0; ni < 4; ++ni) {
        const char* rb = bC + (((wn << 6) + (ni << 4) + fr) << 7);
        bf[ni][0] = *(const bf16x8*)(rb + cb0);
        bf[ni][1] = *(const bf16x8*)(rb + (cb0 ^ 64));
      }
      if (MODE < 2) stage_half(gA1 + HALF_G, aN + 16384, wave);
      asm volatile("s_waitcnt lgkmcnt(8)" ::: "memory");  // 12 ds_reads issued
    }
    if (MODE == 0) {
      if (p == 1) stage_half(gB2, bC, wave);
      if (p == 2) stage_half(gB2 + HALF_G, bC + 16384, wave);
      if (p == 3) stage_half(gA2, aC, wave);
    }
    if (p == 3) {
      if (MODE == 0) asm volatile("s_waitcnt vmcnt(6)" ::: "memory");
      if (MODE == 1) asm volatile("s_waitcnt vmcnt(0)" ::: "memory");
    }
    __builtin_amdgcn_sched_barrier(0);
    __builtin_amdgcn_s_barrier();
    asm volatile("s_waitcnt lgkmcnt(0)" ::: "memory");
    __builtin_amdgcn_sched_barrier(0);
    __builtin_amdgcn_s_setprio(1);
#pragma unroll
    for (int mi = 0; mi < 2; ++mi)
#pragma unroll
      for (int ni = 0; ni < 4; ++ni) {
        acc[(p << 1) + mi][ni] = MFMA(af[mi][0], bf[ni][0], acc[(p << 1) + mi][ni]);
        acc[(p << 1) + mi][ni] = MFMA(af[mi][1], bf[ni][1], acc[(p << 1) + mi][ni]);
      }
    __builtin_amdgcn_s_setprio(0);
    __builtin_amdgcn_s_barrier();
  }
}

// ---------------------------------------------------------------------------
// 256x256 8-phase bf16 GEMM, K=4096.
// 8 waves (2M x 4N): per-wave 128 rows x 64 cols, acc[8][4] f32x4.
// ---------------------------------------------------------------------------
__global__ __launch_bounds__(512, 2) void gemm8(
    const ushort* __restrict__ Xh, const ushort* __restrict__ Wh,
    const float* __restrict__ bias, float* __restrict__ out) {
  __shared__ __align__(16) char lds[131072];

  const int tid = threadIdx.x;
  const int wave = tid >> 6;
  const int lane = tid & 63;
  const int wm = wave & 1;   // 2 waves along M
  const int wn = wave >> 1;  // 4 waves along N

  // T1: XCD-aware bijective swizzle (512 blocks, 512 % 8 == 0)
  const int swz = ((blockIdx.x & 7) << 6) + (blockIdx.x >> 3);
  const int tm = swz >> 4, tn = swz & 15;     // 32 x 16 tiles
  const int brow0 = tm << 8, bcol0 = tn << 8;

  // staging geometry: lds flat f = iss*8192 + wave*1024 + lane*16
  // row = h*128 + iss*64 + wave*8 + (lane>>3); stored-at cb_swz=(lane&7)<<4;
  // logical col = cb_swz ^ ((row&7)<<4)  (involution, row&7 == lane>>3)
  const int s_r0 = (wave << 3) + (lane >> 3);
  const int s_cb = ((lane & 7) ^ (lane >> 3)) << 4;
  const char* gX = (const char*)Xh + (size_t)(brow0 + s_r0) * PITCH_B + s_cb;
  const char* gW = (const char*)Wh + (size_t)(bcol0 + s_r0) * PITCH_B + s_cb;

  // fragment geometry: addr = row*128 + (cb_log ^ ((row&7)<<4)), row&7==lane&7
  const int fr = lane & 15;
  const int cb0 = (((lane >> 4) << 4) ^ ((lane & 7) << 4));

  f32x4 acc[8][4];
#pragma unroll
  for (int i = 0; i < 8; ++i)
#pragma unroll
    for (int j = 0; j < 4; ++j) acc[i][j] = (f32x4){0.f, 0.f, 0.f, 0.f};

  char* A0 = lds;
  char* B0 = lds + 32768;
  char* A1 = lds + 65536;
  char* B1 = lds + 98304;

  // prologue: tile0 {B0,B1,A0,A1} + tile1 {B0,B1,A0h0}; drain to tile0 ready
  {
    const char* gB0s = gW + col_bytes(0);
    const char* gA0s = gX + col_bytes(0);
    const char* gB1s = gW + col_bytes(1);
    const char* gA1s = gX + col_bytes(1);
    stage_half(gB0s, B0, wave);
    stage_half(gB0s + HALF_G, B0 + 16384, wave);
    stage_half(gA0s, A0, wave);
    stage_half(gA0s + HALF_G, A0 + 16384, wave);
    stage_half(gB1s, B1, wave);
    stage_half(gB1s + HALF_G, B1 + 16384, wave);
    stage_half(gA1s, A1, wave);
    asm volatile("s_waitcnt vmcnt(6)" ::: "memory");
    __builtin_amdgcn_s_barrier();
  }

  for (int t = 0; t < NT - 2; ++t) {
    const int bt = t & 1;
    char* aC = lds + (bt << 16);
    char* bC = aC + 32768;
    char* aN = lds + ((bt ^ 1) << 16);
    do_tile<0>(aC, bC, aN, gX + col_bytes(t + 1), gW + col_bytes(t + 2),
               gX + col_bytes(t + 2), wm, wn, wave, fr, cb0, acc);
  }
  // t = NT-2 (= 62, even -> buf0): stage only A(63) half1, drain all
  do_tile<1>(A0, B0, A1, gX + col_bytes(NT - 1), gW, gX, wm, wn, wave, fr, cb0, acc);
  // t = NT-1 (buf1): pure compute
  do_tile<2>(A1, B1, A0, gX, gW, gX, wm, wn, wave, fr, cb0, acc);

  // epilogue: per 16x16 frag, C[col = lane&15, row = (lane>>4)*4 + j]
  const int ccol = bcol0 + (wn << 6) + fr;
  const size_t rbase = (size_t)brow0 + (wm << 7) + ((lane >> 4) << 2);
  float bv[4];
#pragma unroll
  for (int ni = 0; ni < 4; ++ni) bv[ni] = bias[ccol + (ni << 4)];
#pragma unroll
  for (int mi = 0; mi < 8; ++mi) {
#pragma unroll
    for (int j = 0; j < 4; ++j) {
      float* orow = out + (rbase + (mi << 4) + j) * N_DIM;
#pragma unroll
      for (int ni = 0; ni < 4; ++ni)
        orow[ccol + (ni << 4)] = acc[mi][ni][j] + bv[ni];
    }
  }
}

// ---------------------------------------------------------------------------
// Fallback: plain fp32 LDS-tiled GEMM (only if ws too small)
// ---------------------------------------------------------------------------
__global__ __launch_bounds__(256) void gemm_fallback(
    const float* __restrict__ X, const float* __restrict__ W,
    const float* __restrict__ bias, float* __restrict__ out) {
  __shared__ float As[64][17];
  __shared__ float Bs[64][17];
  const int tid = threadIdx.x;
  const int tm = blockIdx.x / (N_DIM / 64);
  const int tn = blockIdx.x % (N_DIM / 64);
  const int ty = tid >> 4, tx = tid & 15;
  float acc[4][4] = {};
  for (int k0 = 0; k0 < K_DIM; k0 += 16) {
#pragma unroll
    for (int i = 0; i < 4; ++i) {
      int idx = tid * 4 + i;
      int r = idx >> 4, c = idx & 15;
      As[r][c] = X[(size_t)(tm * 64 + r) * K_DIM + k0 + c];
      Bs[r][c] = W[(size_t)(tn * 64 + r) * K_DIM + k0 + c];
    }
    __syncthreads();
#pragma unroll
    for (int kk = 0; kk < 16; ++kk)
#pragma unroll
      for (int i = 0; i < 4; ++i)
#pragma unroll
        for (int j = 0; j < 4; ++j)
          acc[i][j] += As[ty * 4 + i][kk] * Bs[tx * 4 + j][kk];
    __syncthreads();
  }
#pragma unroll
  for (int i = 0; i < 4; ++i)
#pragma unroll
    for (int j = 0; j < 4; ++j) {
      int c = tn * 64 + tx * 4 + j;
      out[(size_t)(tm * 64 + ty * 4 + i) * N_DIM + c] = acc[i][j] + bias[c];
    }
}

extern "C" void kernel_launch(void* const* d_in, const int* in_sizes, int n_in,
                              void* d_out, int out_size, void* d_ws, size_t ws_size,
                              hipStream_t stream) {
  const float* X = (const float*)d_in[0];
  const float* W = (const float*)d_in[1];
  const float* bias = (const float*)d_in[2];
  float* out = (float*)d_out;

  const size_t nX = (size_t)M_DIM * K_DIM;
  const size_t nW = (size_t)N_DIM * K_DIM;
  const size_t needed = (nX + nW) * sizeof(ushort);

  if (ws_size >= needed) {
    ushort* Xh = (ushort*)d_ws;
    ushort* Wh = Xh + nX;
    convert_bf16<<<2048, 256, 0, stream>>>(X, Xh, (long)nX);
    convert_bf16<<<1024, 256, 0, stream>>>(W, Wh, (long)nW);
    gemm8<<<512, 512, 0, stream>>>(Xh, Wh, bias, out);
  } else {
    gemm_fallback<<<(M_DIM / 64) * (N_DIM / 64), 256, 0, stream>>>(X, W, bias, out);
  }
}